// Round 7
// baseline (122988.745 us; speedup 1.0000x reference)
//
#include <hip/hip_runtime.h>
#include <math.h>

#define NB  256      // batch
#define NYD 256      // y dim
#define NL  1024     // latents
#define NT  512      // time steps
#define KIN (2*NYD)  // 512

__device__ __forceinline__ float sigmoidf_(float x) { return 1.0f / (1.0f + expf(-x)); }

__device__ __forceinline__ int mask_at(const void* mp, int mode, int idx) {
    if (mode == 1) return ((const unsigned char*)mp)[idx] != 0;
    if (mode == 2) return ((const float*)mp)[idx] != 0.0f;
    return ((const int*)mp)[idx] != 0;
}

__device__ __forceinline__ float sel4(const float (&a)[4], int kl) {
    float v = a[0];
    v = (kl == 1) ? a[1] : v;
    v = (kl == 2) ? a[2] : v;
    v = (kl == 3) ? a[3] : v;
    return v;
}

__device__ __forceinline__ void red2(float (&a)[4][4]) {
#pragma unroll
    for (int s = 0; s < 4; ++s)
#pragma unroll
        for (int n = 0; n < 4; ++n) {
            float v = a[s][n];
            v += __shfl_xor(v, 1, 64);
            v += __shfl_xor(v, 2, 64);
            a[s][n] = v;
        }
}

// ================= persistent-kernel path =================

// ---- two-level monotonic grid barrier (co-residency via cooperative launch) ----
__device__ __forceinline__ void gbar(unsigned* bar, unsigned& ep) {
    ++ep;
    __syncthreads();
    if (threadIdx.x == 0) {
        __threadfence();                   // agent release
        const int g = blockIdx.x >> 4;     // 16 groups of 16 blocks
        unsigned* grp  = bar + g * 32;     // 128B-separated counters
        unsigned* root = bar + 16 * 32;
        unsigned* flag = bar + 16 * 32 + 32;
        unsigned old = __hip_atomic_fetch_add(grp, 1u, __ATOMIC_ACQ_REL, __HIP_MEMORY_SCOPE_AGENT);
        if (old == 16u * ep - 1u) {
            unsigned r = __hip_atomic_fetch_add(root, 1u, __ATOMIC_ACQ_REL, __HIP_MEMORY_SCOPE_AGENT);
            if (r == 16u * ep - 1u)
                __hip_atomic_store(flag, ep, __ATOMIC_RELEASE, __HIP_MEMORY_SCOPE_AGENT);
        }
        // timeout insurance: lost sync -> garbage output + EXIT, never a wedge.
        unsigned cnt = 0;
        while (__hip_atomic_load(flag, __ATOMIC_ACQUIRE, __HIP_MEMORY_SCOPE_AGENT) < ep) {
            __builtin_amdgcn_s_sleep(2);
            if (++cnt > 200000u) break;
        }
        __threadfence();                   // agent acquire
    }
    __syncthreads();
}

// ---- skinny dot: 4 LDS weight rows (pitch 1024), K = NJ*16, acc[s][n] ----
template<int NJ>
__device__ __forceinline__ void dot4(
        const float* __restrict__ base, const int pitch,
        const float (&wlds)[4 * 1024],
        const int bq, const int kl, const int wb0,
        float (&ac)[4][4]) {
    int off[4];
#pragma unroll
    for (int s = 0; s < 4; ++s) off[s] = (wb0 + s * 16 + bq) * pitch + kl * 4;
    const float* wp = &wlds[kl * 4];
    float4 A0[4], A1[4];
#pragma unroll
    for (int s = 0; s < 4; ++s) A0[s] = *(const float4*)(base + off[s]);
#pragma unroll
    for (int s = 0; s < 4; ++s) A1[s] = *(const float4*)(base + off[s] + 16);
#pragma unroll 1
    for (int j = 0; j < NJ; j += 2) {
        float4 w[4];
#pragma unroll
        for (int n = 0; n < 4; ++n) w[n] = *(const float4*)(wp + n * 1024 + 16 * j);
#pragma unroll
        for (int s = 0; s < 4; ++s) {
            float4 a = A0[s];
#pragma unroll
            for (int n = 0; n < 4; ++n)
                ac[s][n] += a.x * w[n].x + a.y * w[n].y + a.z * w[n].z + a.w * w[n].w;
        }
        if (j + 2 < NJ) {
#pragma unroll
            for (int s = 0; s < 4; ++s) A0[s] = *(const float4*)(base + off[s] + 16 * (j + 2));
        }
        float4 w1[4];
#pragma unroll
        for (int n = 0; n < 4; ++n) w1[n] = *(const float4*)(wp + n * 1024 + 16 * (j + 1));
#pragma unroll
        for (int s = 0; s < 4; ++s) {
            float4 a = A1[s];
#pragma unroll
            for (int n = 0; n < 4; ++n)
                ac[s][n] += a.x * w1[n].x + a.y * w1[n].y + a.z * w1[n].z + a.w * w1[n].w;
        }
        if (j + 3 < NJ) {
#pragma unroll
            for (int s = 0; s < 4; ++s) A1[s] = *(const float4*)(base + off[s] + 16 * (j + 3));
        }
    }
}

// ---- gates dot: 12 LDS weight rows (pitch 1536), acc split r/z/n ----
template<int NJ>
__device__ __forceinline__ void dotA(
        const float* __restrict__ base, const int pitch, const int wc0,
        const float (&wlds)[12 * 1536],
        const int bq, const int kl, const int wb0,
        float (&ar)[4][4], float (&az)[4][4], float (&an)[4][4]) {
    int off[4];
#pragma unroll
    for (int s = 0; s < 4; ++s) off[s] = (wb0 + s * 16 + bq) * pitch + kl * 4;
    const float* wp = &wlds[wc0 + kl * 4];
    float4 A0[4], A1[4];
#pragma unroll
    for (int s = 0; s < 4; ++s) A0[s] = *(const float4*)(base + off[s]);
#pragma unroll
    for (int s = 0; s < 4; ++s) A1[s] = *(const float4*)(base + off[s] + 16);
#pragma unroll 1
    for (int j = 0; j < NJ; j += 2) {
        float4 w[12];
#pragma unroll
        for (int n = 0; n < 12; ++n) w[n] = *(const float4*)(wp + n * 1536 + 16 * j);
#pragma unroll
        for (int s = 0; s < 4; ++s) {
            float4 a = A0[s];
#pragma unroll
            for (int n = 0; n < 4; ++n) {
                ar[s][n] += a.x * w[n].x     + a.y * w[n].y     + a.z * w[n].z     + a.w * w[n].w;
                az[s][n] += a.x * w[4 + n].x + a.y * w[4 + n].y + a.z * w[4 + n].z + a.w * w[4 + n].w;
                an[s][n] += a.x * w[8 + n].x + a.y * w[8 + n].y + a.z * w[8 + n].z + a.w * w[8 + n].w;
            }
        }
        if (j + 2 < NJ) {
#pragma unroll
            for (int s = 0; s < 4; ++s) A0[s] = *(const float4*)(base + off[s] + 16 * (j + 2));
        }
        float4 w1[12];
#pragma unroll
        for (int n = 0; n < 12; ++n) w1[n] = *(const float4*)(wp + n * 1536 + 16 * (j + 1));
#pragma unroll
        for (int s = 0; s < 4; ++s) {
            float4 a = A1[s];
#pragma unroll
            for (int n = 0; n < 4; ++n) {
                ar[s][n] += a.x * w1[n].x     + a.y * w1[n].y     + a.z * w1[n].z     + a.w * w1[n].w;
                az[s][n] += a.x * w1[4 + n].x + a.y * w1[4 + n].y + a.z * w1[4 + n].z + a.w * w1[4 + n].w;
                an[s][n] += a.x * w1[8 + n].x + a.y * w1[8 + n].y + a.z * w1[8 + n].z + a.w * w1[8 + n].w;
            }
        }
        if (j + 3 < NJ) {
#pragma unroll
            for (int s = 0; s < 4; ++s) A1[s] = *(const float4*)(base + off[s] + 16 * (j + 3));
        }
    }
}

__global__ void zero_bar_kernel(unsigned* __restrict__ bar) {
    bar[blockIdx.x * 256 + threadIdx.x] = 0u;
}

__global__ __launch_bounds__(256, 1) void gru_persist(
        const float* __restrict__ x,
        const float* __restrict__ y,
        const void*  __restrict__ ymask,
        const float* __restrict__ W_beta, const float* __restrict__ b_beta,
        const float* __restrict__ W_ih,   const float* __restrict__ b_ih,
        const float* __restrict__ W_hh,   const float* __restrict__ b_hh,
        const float* __restrict__ W_out,  const float* __restrict__ b_out,
        float* __restrict__ out,
        float* __restrict__ h0buf, float* __restrict__ h1buf,
        float2* __restrict__ gin2, unsigned* __restrict__ bar) {
    __shared__ float Wsh[12 * 1536];   // fused [W_ih | W_hh] rows: r0..3, z0..3, n0..3
    __shared__ float Wxsh[4 * 1024];   // W_beta rows (init) then W_out rows (blocks<64)

    const int bid = blockIdx.x;
    const int tid = threadIdx.x;
    const int lane = tid & 63;
    const int wv   = tid >> 6;
    const int bq   = lane >> 2;
    const int kl   = lane & 3;
    const int wb0  = wv * 64;
    const int l0   = bid * 4;
    const int d0   = (bid & 63) * 4;
    const float* ginf = (const float*)gin2;

    int mode = 0;
    {
        bool not01 = false, notf = false;
        const unsigned* mw = (const unsigned*)ymask;
        for (int i = 0; i < 64; ++i) {
            unsigned v = mw[i];
            if (v > 1u) not01 = true;
            if (v != 0u && v != 0x3f800000u) notf = true;
        }
        if (not01) mode = notf ? 1 : 2;
    }

    for (int i = 0; i < 18; ++i) {                  // 18*256 = 4608 float4
        int idx = tid + 256 * i;
        int n = idx / 384, c4 = idx - n * 384;
        int col = c4 * 4;
        int g = n >> 2, l = n & 3;
        int grow = g * NL + l0 + l;
        float4 v = (col < 512)
            ? *(const float4*)&W_ih[grow * 512 + col]
            : *(const float4*)&W_hh[grow * NL + (col - 512)];
        *(float4*)&Wsh[n * 1536 + col] = v;
    }
    for (int i = 0; i < 4; ++i) {
        int idx = tid + 256 * i;
        int r = idx >> 8, c4 = idx & 255;
        *(float4*)&Wxsh[r * 1024 + c4 * 4] = *(const float4*)&W_beta[(l0 + r) * NL + c4 * 4];
    }
    __syncthreads();

    {   // h0 = x @ W_beta.T + b_beta
        float ac[4][4] = {};
        dot4<64>(x, NL, Wxsh, bq, kl, wb0, ac);
        red2(ac);
        float bb = b_beta[l0 + kl];
#pragma unroll
        for (int s = 0; s < 4; ++s) {
            int b = wb0 + s * 16 + bq;
            h0buf[b * NL + l0 + kl] = sel4(ac[s], kl) + bb;
        }
    }
    if (bid < 64) {
        for (int dd = 0; dd < 4; ++dd) {
            int b = tid, d = d0 + dd;
            int idx = (b * NYD + d) * NT;
            int m = mask_at(ymask, mode, idx);
            gin2[b * NYD + d] = make_float2(m ? y[idx] : 0.0f, (float)m);
        }
    }
    __syncthreads();
    if (bid < 64) {
        for (int i = 0; i < 4; ++i) {
            int idx = tid + 256 * i;
            int r = idx >> 8, c4 = idx & 255;
            *(float4*)&Wxsh[r * 1024 + c4 * 4] = *(const float4*)&W_out[(d0 + r) * NL + c4 * 4];
        }
    }

    const int lA = l0 + kl;
    const float brA  = b_ih[lA] + b_hh[lA];
    const float bzA  = b_ih[NL + lA] + b_hh[NL + lA];
    const float bniA = b_ih[2 * NL + lA];
    const float bnhA = b_hh[2 * NL + lA];
    const float boB  = (bid < 64) ? b_out[d0 + kl] : 0.0f;

    unsigned ep = 0;
    gbar(bar, ep);

    for (int t = 0; t < NT; ++t) {
        const float* hp = (t & 1) ? h1buf : h0buf;
        float*       hn = (t & 1) ? h0buf : h1buf;

        {   // phase A: gates + h_new
            float ar[4][4] = {}, az[4][4] = {}, ani[4][4] = {}, anh[4][4] = {};
            dotA<32>(ginf, 512, 0,   Wsh, bq, kl, wb0, ar, az, ani);
            dotA<64>(hp,   NL,  512, Wsh, bq, kl, wb0, ar, az, anh);
            red2(ar); red2(az); red2(ani); red2(anh);
#pragma unroll
            for (int s = 0; s < 4; ++s) {
                int b = wb0 + s * 16 + bq;
                float vr = sel4(ar[s], kl) + brA;
                float vz = sel4(az[s], kl) + bzA;
                float vi = sel4(ani[s], kl) + bniA;
                float vh = sel4(anh[s], kl) + bnhA;
                float r = sigmoidf_(vr);
                float z = sigmoidf_(vz);
                float n = tanhf(vi + r * vh);
                float hpv = hp[b * NL + lA];
                hn[b * NL + lA] = (1.0f - z) * n + z * hpv;
            }
        }
        gbar(bar, ep);

        if (bid < 64) {   // phase B: out + next gin
            float ac[4][4] = {};
            dot4<64>(hn, NL, Wxsh, bq, kl, wb0, ac);
            red2(ac);
            const int d = d0 + kl;
#pragma unroll
            for (int s = 0; s < 4; ++s) {
                int b = wb0 + s * 16 + bq;
                float o = sel4(ac[s], kl) + boB;
                int oidx = (b * NYD + d) * NT + t;
                out[oidx] = o;
                if (t + 1 < NT) {
                    int yi = oidx + 1;
                    int m = mask_at(ymask, mode, yi);
                    gin2[b * NYD + d] = make_float2(m ? y[yi] : o, (float)m);
                }
            }
        }
        gbar(bar, ep);
    }
}

// ================= fallback path (round-1, known-passing) =================

__global__ void probe_mask_kernel(const unsigned int* __restrict__ mw,
                                  int* __restrict__ flag) {
    __shared__ int not01, notf;
    if (threadIdx.x == 0) { not01 = 0; notf = 0; }
    __syncthreads();
    unsigned int v = mw[threadIdx.x];
    if (v > 1u) not01 = 1;
    if (v != 0u && v != 0x3f800000u) notf = 1;
    __syncthreads();
    if (threadIdx.x == 0) {
        int mode = 0;
        if (not01) mode = notf ? 1 : 2;
        *flag = mode;
    }
}

__global__ __launch_bounds__(256) void init_h_kernel(
        const float* __restrict__ x, const float* __restrict__ Wb,
        const float* __restrict__ bb, float* __restrict__ h0) {
    int idx = blockIdx.x * 256 + threadIdx.x;
    int b = idx >> 10;
    int l = idx & 1023;
    const float4* xr = (const float4*)(x + b * 1024);
    const float4* wr = (const float4*)(Wb + l * 1024);
    float acc = bb[l];
#pragma unroll 4
    for (int k = 0; k < 256; ++k) {
        float4 xv = xr[k];
        float4 wv = wr[k];
        acc += xv.x*wv.x + xv.y*wv.y + xv.z*wv.z + xv.w*wv.w;
    }
    h0[idx] = acc;
}

__global__ __launch_bounds__(NYD) void init_gru0_kernel(
        const float* __restrict__ y, const void* __restrict__ ymask,
        const int* __restrict__ mflag, float2* __restrict__ gin) {
    int b = blockIdx.x;
    int d = threadIdx.x;
    int mode = *mflag;
    int idx = (b * NYD + d) * NT;
    int m = mask_at(ymask, mode, idx);
    float yv = m ? y[idx] : 0.0f;
    gin[b * NYD + d] = make_float2(yv, (float)m);
}

template<int NIT>
__device__ __forceinline__ void gemm_phase(
        const float* __restrict__ A, int pitch,
        const float* __restrict__ W,
        int l0, int tid, int bg, int lth,
        float (&Ash)[16][32], float (&Wsh)[3][32][32],
        float* accr, float* accz, float* accn) {
    const int arow = tid >> 3;
    const int akc  = (tid & 7) * 4;
    float4 areg, wreg[6];
    int wrow[6], wg[6], wkc[6];
#pragma unroll
    for (int i = 0; i < 6; ++i) {
        int idx = tid + 128 * i;
        wkc[i]  = (idx & 7) * 4;
        wrow[i] = (idx >> 3) & 31;
        wg[i]   = idx >> 8;
    }
    areg = *(const float4*)(A + arow * pitch + akc);
#pragma unroll
    for (int i = 0; i < 6; ++i)
        wreg[i] = *(const float4*)(W + (wg[i]*NL + l0 + wrow[i]) * pitch + wkc[i]);
    *(float4*)&Ash[arow][akc] = areg;
#pragma unroll
    for (int i = 0; i < 6; ++i)
        *(float4*)&Wsh[wg[i]][wrow[i]][wkc[i] ^ ((wrow[i] & 7) << 2)] = wreg[i];
    __syncthreads();

    const int wsw = (lth & 7) << 2;
    for (int it = 0; it < NIT; ++it) {
        const int k0n = (it + 1) * 32;
        if (it + 1 < NIT) {
            areg = *(const float4*)(A + arow * pitch + k0n + akc);
#pragma unroll
            for (int i = 0; i < 6; ++i)
                wreg[i] = *(const float4*)(W + (wg[i]*NL + l0 + wrow[i]) * pitch + k0n + wkc[i]);
        }
#pragma unroll
        for (int kk = 0; kk < 8; ++kk) {
            float4 wr_ = *(const float4*)&Wsh[0][lth][(kk*4) ^ wsw];
            float4 wz_ = *(const float4*)&Wsh[1][lth][(kk*4) ^ wsw];
            float4 wn_ = *(const float4*)&Wsh[2][lth][(kk*4) ^ wsw];
#pragma unroll
            for (int i = 0; i < 4; ++i) {
                float4 av = *(const float4*)&Ash[bg*4 + i][kk*4];
                accr[i] += av.x*wr_.x + av.y*wr_.y + av.z*wr_.z + av.w*wr_.w;
                accz[i] += av.x*wz_.x + av.y*wz_.y + av.z*wz_.z + av.w*wz_.w;
                accn[i] += av.x*wn_.x + av.y*wn_.y + av.z*wn_.z + av.w*wn_.w;
            }
        }
        __syncthreads();
        if (it + 1 < NIT) {
            *(float4*)&Ash[arow][akc] = areg;
#pragma unroll
            for (int i = 0; i < 6; ++i)
                *(float4*)&Wsh[wg[i]][wrow[i]][wkc[i] ^ ((wrow[i] & 7) << 2)] = wreg[i];
            __syncthreads();
        }
    }
}

__global__ __launch_bounds__(128) void step_gates_kernel(
        const float* __restrict__ h_prev, float* __restrict__ h_next,
        const float* __restrict__ gin,
        const float* __restrict__ W_ih, const float* __restrict__ b_ih,
        const float* __restrict__ W_hh, const float* __restrict__ b_hh) {
    const int b0 = blockIdx.x * 16;
    const int l0 = blockIdx.y * 32;
    const int tid = threadIdx.x;
    const int lth = tid & 31;
    const int bg  = tid >> 5;
    __shared__ float Ash[16][32];
    __shared__ float Wsh[3][32][32];

    float accr[4]  = {0.f, 0.f, 0.f, 0.f};
    float accz[4]  = {0.f, 0.f, 0.f, 0.f};
    float accni[4] = {0.f, 0.f, 0.f, 0.f};
    float accnh[4] = {0.f, 0.f, 0.f, 0.f};

    gemm_phase<KIN/32>(gin    + b0*KIN, KIN, W_ih, l0, tid, bg, lth, Ash, Wsh, accr, accz, accni);
    gemm_phase<NL/32 >(h_prev + b0*NL,  NL,  W_hh, l0, tid, bg, lth, Ash, Wsh, accr, accz, accnh);

    const int l = l0 + lth;
    const float br  = b_ih[l]        + b_hh[l];
    const float bz  = b_ih[NL + l]   + b_hh[NL + l];
    const float bni = b_ih[2*NL + l];
    const float bnh = b_hh[2*NL + l];
#pragma unroll
    for (int i = 0; i < 4; ++i) {
        const int b = b0 + bg*4 + i;
        float r = sigmoidf_(accr[i] + br);
        float z = sigmoidf_(accz[i] + bz);
        float n = tanhf(accni[i] + bni + r * (accnh[i] + bnh));
        float hp = h_prev[b*NL + l];
        h_next[b*NL + l] = (1.0f - z)*n + z*hp;
    }
}

__global__ __launch_bounds__(128) void step_out_kernel(
        const float* __restrict__ h, const float* __restrict__ W_out,
        const float* __restrict__ b_out, const float* __restrict__ y,
        const void* __restrict__ ymask, const int* __restrict__ mflag,
        float* __restrict__ out, float2* __restrict__ gin, int t) {
    const int b0 = blockIdx.x * 16;
    const int d0 = blockIdx.y * 32;
    const int tid = threadIdx.x;
    const int dth = tid & 31;
    const int bg  = tid >> 5;
    __shared__ float Ash[16][32];
    __shared__ float Wsh[32][32];
    float acc[4] = {0.f, 0.f, 0.f, 0.f};

    const int arow = tid >> 3;
    const int akc  = (tid & 7) * 4;
    float4 areg, wreg[2];
    int wrow[2], wkc[2];
#pragma unroll
    for (int i = 0; i < 2; ++i) {
        int idx = tid + 128 * i;
        wkc[i]  = (idx & 7) * 4;
        wrow[i] = idx >> 3;
    }
    const float* A = h + b0 * NL;
    areg = *(const float4*)(A + arow * NL + akc);
#pragma unroll
    for (int i = 0; i < 2; ++i)
        wreg[i] = *(const float4*)(W_out + (d0 + wrow[i]) * NL + wkc[i]);
    *(float4*)&Ash[arow][akc] = areg;
#pragma unroll
    for (int i = 0; i < 2; ++i)
        *(float4*)&Wsh[wrow[i]][wkc[i] ^ ((wrow[i] & 7) << 2)] = wreg[i];
    __syncthreads();

    const int wsw = (dth & 7) << 2;
    for (int it = 0; it < NL/32; ++it) {
        const int k0n = (it + 1) * 32;
        if (it + 1 < NL/32) {
            areg = *(const float4*)(A + arow * NL + k0n + akc);
#pragma unroll
            for (int i = 0; i < 2; ++i)
                wreg[i] = *(const float4*)(W_out + (d0 + wrow[i]) * NL + k0n + wkc[i]);
        }
#pragma unroll
        for (int kk = 0; kk < 8; ++kk) {
            float4 wv = *(const float4*)&Wsh[dth][(kk*4) ^ wsw];
#pragma unroll
            for (int i = 0; i < 4; ++i) {
                float4 av = *(const float4*)&Ash[bg*4 + i][kk*4];
                acc[i] += av.x*wv.x + av.y*wv.y + av.z*wv.z + av.w*wv.w;
            }
        }
        __syncthreads();
        if (it + 1 < NL/32) {
            *(float4*)&Ash[arow][akc] = areg;
#pragma unroll
            for (int i = 0; i < 2; ++i)
                *(float4*)&Wsh[wrow[i]][wkc[i] ^ ((wrow[i] & 7) << 2)] = wreg[i];
            __syncthreads();
        }
    }

    const int d = d0 + dth;
    const float bo = b_out[d];
    const int mode = *mflag;
#pragma unroll
    for (int i = 0; i < 4; ++i) {
        const int b = b0 + bg*4 + i;
        float o = acc[i] + bo;
        out[(b*NYD + d)*NT + t] = o;
        if (t + 1 < NT) {
            int idx = (b*NYD + d)*NT + (t + 1);
            int m = mask_at(ymask, mode, idx);
            float yv = m ? y[idx] : o;
            gin[b*NYD + d] = make_float2(yv, (float)m);
        }
    }
}

// ================= launch =================

extern "C" void kernel_launch(void* const* d_in, const int* in_sizes, int n_in,
                              void* d_out, int out_size, void* d_ws, size_t ws_size,
                              hipStream_t stream) {
    (void)in_sizes; (void)n_in; (void)out_size; (void)ws_size;
    const float* x      = (const float*)d_in[0];
    const float* y      = (const float*)d_in[1];
    const void*  ymask  = d_in[2];
    const float* W_beta = (const float*)d_in[3];
    const float* b_beta = (const float*)d_in[4];
    const float* W_ih   = (const float*)d_in[5];
    const float* b_ih   = (const float*)d_in[6];
    const float* W_hh   = (const float*)d_in[7];
    const float* b_hh   = (const float*)d_in[8];
    const float* W_out  = (const float*)d_in[9];
    const float* b_out  = (const float*)d_in[10];
    float* out = (float*)d_out;

    float*    ws    = (float*)d_ws;
    float*    h0buf = ws;                               // 1 MB
    float*    h1buf = ws + NB * NL;                     // 1 MB
    float2*   gin2  = (float2*)(ws + 2 * NB * NL);      // 512 KB
    unsigned* bar   = (unsigned*)(ws + 2 * NB * NL + 2 * NB * NYD);   // 4 KB
    int*      mflag = (int*)(bar + 1024);

    zero_bar_kernel<<<4, 256, 0, stream>>>(bar);

    void* args[] = { (void*)&x, (void*)&y, (void*)&ymask,
                     (void*)&W_beta, (void*)&b_beta,
                     (void*)&W_ih, (void*)&b_ih,
                     (void*)&W_hh, (void*)&b_hh,
                     (void*)&W_out, (void*)&b_out,
                     (void*)&out, (void*)&h0buf, (void*)&h1buf,
                     (void*)&gin2, (void*)&bar };
    hipError_t err = hipLaunchCooperativeKernel((const void*)gru_persist,
                                                dim3(256), dim3(256),
                                                args, 0, stream);
    if (err != hipSuccess) {
        // deterministic per-environment fallback: round-1 proven per-step path
        probe_mask_kernel<<<1, 256, 0, stream>>>((const unsigned int*)ymask, mflag);
        init_h_kernel<<<NB*NL/256, 256, 0, stream>>>(x, W_beta, b_beta, h0buf);
        init_gru0_kernel<<<NB, NYD, 0, stream>>>(y, ymask, mflag, gin2);
        for (int t = 0; t < NT; ++t) {
            float* hp = (t & 1) ? h1buf : h0buf;
            float* hn = (t & 1) ? h0buf : h1buf;
            dim3 ggrid(16, 32);
            step_gates_kernel<<<ggrid, 128, 0, stream>>>(
                hp, hn, (const float*)gin2, W_ih, b_ih, W_hh, b_hh);
            dim3 ogrid(16, 8);
            step_out_kernel<<<ogrid, 128, 0, stream>>>(
                hn, W_out, b_out, y, ymask, mflag, out, gin2, t);
        }
    }
}

// Round 8
// 64284.314 us; speedup vs baseline: 1.9132x; 1.9132x over previous
//
#include <hip/hip_runtime.h>
#include <math.h>

#define NB  256      // batch
#define NYD 256      // y dim
#define NL  1024     // latents
#define NT  512      // time steps
#define KIN (2*NYD)  // 512

__device__ __forceinline__ float sigmoidf_(float x) { return 1.0f / (1.0f + expf(-x)); }

__device__ __forceinline__ int mask_at(const void* mp, int mode, int idx) {
    if (mode == 1) return ((const unsigned char*)mp)[idx] != 0;
    if (mode == 2) return ((const float*)mp)[idx] != 0.0f;
    return ((const int*)mp)[idx] != 0;
}

__device__ __forceinline__ float dot4f(const float4 a, const float4 w) {
    return a.x*w.x + a.y*w.y + a.z*w.z + a.w*w.w;
}

__device__ __forceinline__ float sel4(const float (&a)[4], int i) {
    float v = a[0];
    v = (i == 1) ? a[1] : v;
    v = (i == 2) ? a[2] : v;
    v = (i == 3) ? a[3] : v;
    return v;
}

__device__ __forceinline__ float c4(const float4 v, int i) {
    float r = v.x;
    r = (i == 1) ? v.y : r;
    r = (i == 2) ? v.z : r;
    r = (i == 3) ? v.w : r;
    return r;
}

__device__ __forceinline__ float sel16(const float (&a)[4][4], int l, int s) {
    float v0 = sel4(a[0], s);
    float v1 = sel4(a[1], s);
    float v2 = sel4(a[2], s);
    float v3 = sel4(a[3], s);
    float v = v0;
    v = (l == 1) ? v1 : v;
    v = (l == 2) ? v2 : v;
    v = (l == 3) ? v3 : v;
    return v;
}

// reduce over 8-lane K-groups (xor 1,2,4)
__device__ __forceinline__ void red8(float (&a)[4][4]) {
#pragma unroll
    for (int n = 0; n < 4; ++n)
#pragma unroll
        for (int s = 0; s < 4; ++s) {
            float v = a[n][s];
            v += __shfl_xor(v, 1, 64);
            v += __shfl_xor(v, 2, 64);
            v += __shfl_xor(v, 4, 64);
            a[n][s] = v;
        }
}

// ================= persistent-kernel path =================

__device__ __forceinline__ void gbar(unsigned* bar, unsigned& ep) {
    ++ep;
    __syncthreads();
    if (threadIdx.x == 0) {
        __threadfence();                   // agent release
        const int g = blockIdx.x >> 4;     // 16 groups of 16 blocks
        unsigned* grp  = bar + g * 32;
        unsigned* root = bar + 16 * 32;
        unsigned* flag = bar + 16 * 32 + 32;
        unsigned old = __hip_atomic_fetch_add(grp, 1u, __ATOMIC_ACQ_REL, __HIP_MEMORY_SCOPE_AGENT);
        if (old == 16u * ep - 1u) {
            unsigned r = __hip_atomic_fetch_add(root, 1u, __ATOMIC_ACQ_REL, __HIP_MEMORY_SCOPE_AGENT);
            if (r == 16u * ep - 1u)
                __hip_atomic_store(flag, ep, __ATOMIC_RELEASE, __HIP_MEMORY_SCOPE_AGENT);
        }
        unsigned cnt = 0;   // timeout insurance: garbage + exit, never a wedge
        while (__hip_atomic_load(flag, __ATOMIC_ACQUIRE, __HIP_MEMORY_SCOPE_AGENT) < ep) {
            __builtin_amdgcn_s_sleep(2);
            if (++cnt > 200000u) break;
        }
        __threadfence();                   // agent acquire
    }
    __syncthreads();
}

// gates dot: 12 weight rows (pitch 1536) in LDS, K-split 8-wide across lanes.
// acc [l-row][s-batch]; batch b = wb0 + s*8 + bq.
template<int NJ>
__device__ __forceinline__ void dotG(
        const float* __restrict__ A, const int pitch, const int wcol0,
        const float (&W)[12 * 1536],
        const int bq, const int kl, const int wb0,
        float (&ar)[4][4], float (&az)[4][4], float (&an)[4][4]) {
    int aoff[4];
#pragma unroll
    for (int s = 0; s < 4; ++s) aoff[s] = (wb0 + s * 8 + bq) * pitch + kl * 4;
    const float* wp = &W[wcol0 + kl * 4];
    float4 A0[4];
#pragma unroll
    for (int s = 0; s < 4; ++s) A0[s] = *(const float4*)(A + aoff[s]);
#pragma unroll 1
    for (int j = 0; j < NJ; ++j) {
        float4 w[12];
#pragma unroll
        for (int n = 0; n < 12; ++n) w[n] = *(const float4*)(wp + n * 1536 + 32 * j);
        float4 Ac[4];
#pragma unroll
        for (int s = 0; s < 4; ++s) Ac[s] = A0[s];
        const int jn = (j + 1 < NJ) ? (j + 1) : j;
#pragma unroll
        for (int s = 0; s < 4; ++s) A0[s] = *(const float4*)(A + aoff[s] + 32 * jn);
#pragma unroll
        for (int s = 0; s < 4; ++s) {
#pragma unroll
            for (int n = 0; n < 4; ++n) {
                ar[n][s] += dot4f(Ac[s], w[n]);
                az[n][s] += dot4f(Ac[s], w[4 + n]);
                an[n][s] += dot4f(Ac[s], w[8 + n]);
            }
        }
    }
}

// 4-row dot (beta / h0): acc [l][s], pitch 1024 both sides, K=1024
__device__ __forceinline__ void dotB4(
        const float* __restrict__ A,
        const float (&W)[4 * 1024],
        const int bq, const int kl, const int wb0,
        float (&ac)[4][4]) {
    int aoff[4];
#pragma unroll
    for (int s = 0; s < 4; ++s) aoff[s] = (wb0 + s * 8 + bq) * 1024 + kl * 4;
    const float* wp = &W[kl * 4];
    float4 A0[4];
#pragma unroll
    for (int s = 0; s < 4; ++s) A0[s] = *(const float4*)(A + aoff[s]);
#pragma unroll 1
    for (int j = 0; j < 32; ++j) {
        float4 w[4];
#pragma unroll
        for (int n = 0; n < 4; ++n) w[n] = *(const float4*)(wp + n * 1024 + 32 * j);
        float4 Ac[4];
#pragma unroll
        for (int s = 0; s < 4; ++s) Ac[s] = A0[s];
        const int jn = (j + 1 < 32) ? (j + 1) : j;
#pragma unroll
        for (int s = 0; s < 4; ++s) A0[s] = *(const float4*)(A + aoff[s] + 32 * jn);
#pragma unroll
        for (int s = 0; s < 4; ++s)
#pragma unroll
            for (int n = 0; n < 4; ++n) ac[n][s] += dot4f(Ac[s], w[n]);
    }
}

__global__ void zero_bar_kernel(unsigned* __restrict__ bar) {
    bar[blockIdx.x * 256 + threadIdx.x] = 0u;
}

__global__ __launch_bounds__(512, 2) void gru_persist(
        const float* __restrict__ x,
        const float* __restrict__ y,
        const void*  __restrict__ ymask,
        const float* __restrict__ W_beta, const float* __restrict__ b_beta,
        const float* __restrict__ W_ih,   const float* __restrict__ b_ih,
        const float* __restrict__ W_hh,   const float* __restrict__ b_hh,
        const float* __restrict__ W_out,  const float* __restrict__ b_out,
        float* __restrict__ out,
        float* __restrict__ h0buf, float* __restrict__ h1buf,
        float2* __restrict__ gin2, unsigned* __restrict__ bar) {
    __shared__ float Wsh[12 * 1536];   // fused [W_ih | W_hh] rows: r0..3,z0..3,n0..3 (72 KB)
    __shared__ float Wxsh[4 * 1024];   // W_beta rows (init), then W_out rows (16 KB)

    const int bid = blockIdx.x;        // 256 blocks, 1/CU
    const int tid = threadIdx.x;       // 512 threads = 8 waves
    const int lane = tid & 63;
    const int wv   = tid >> 6;         // 0..7
    const int bq   = lane >> 3;        // 0..7 batch-within-group
    const int kl   = lane & 7;         // 0..7 K-slice
    const int wb0  = wv * 32;          // phase-A wave batch base (32 b/wave)
    const int l0   = bid * 4;          // this block's 4 latent rows
    const int dt   = bid & 63;         // phase-B d-tile
    const int bt   = bid >> 6;         // phase-B b-tile (0..3)
    const int d0   = dt * 4;
    const float* ginf = (const float*)gin2;

    // ---- mask dtype detect ----
    int mode = 0;
    {
        bool not01 = false, notf = false;
        const unsigned* mw = (const unsigned*)ymask;
        for (int i = 0; i < 64; ++i) {
            unsigned v = mw[i];
            if (v > 1u) not01 = true;
            if (v != 0u && v != 0x3f800000u) notf = true;
        }
        if (not01) mode = notf ? 1 : 2;
    }

    // ---- stage fused gate weights ----
    for (int i = 0; i < 9; ++i) {                   // 9*512 = 4608 float4
        int idx = tid + 512 * i;
        int n = idx / 384, cc = idx - n * 384;
        int col = cc * 4;
        int g = n >> 2, l = n & 3;
        int grow = g * NL + l0 + l;
        float4 v = (col < 512)
            ? *(const float4*)&W_ih[grow * 512 + col]
            : *(const float4*)&W_hh[grow * NL + (col - 512)];
        *(float4*)&Wsh[n * 1536 + col] = v;
    }
    // ---- stage W_beta rows into Wxsh ----
    for (int i = 0; i < 2; ++i) {                   // 2*512 = 1024 float4
        int idx = tid + 512 * i;
        int r = idx >> 8, cc = idx & 255;
        *(float4*)&Wxsh[r * 1024 + cc * 4] = *(const float4*)&W_beta[(l0 + r) * NL + cc * 4];
    }
    __syncthreads();

    // ---- h0 = x @ W_beta.T + b_beta ----
    {
        float ab[4][4] = {};
        dotB4(x, Wxsh, bq, kl, wb0, ab);
        red8(ab);
        float4 bb4 = *(const float4*)&b_beta[l0];
#pragma unroll
        for (int e = 0; e < 2; ++e) {
            int cidx = kl * 2 + e;
            int s = cidx >> 2, l = cidx & 3;
            int b = wb0 + s * 8 + bq;
            h0buf[b * NL + l0 + l] = sel16(ab, l, s) + c4(bb4, l);
        }
    }
    // ---- gin for t=0 (prev prediction = 0): blocks 0..127 cover 65536 entries ----
    if (bid < 128) {
        int idx = bid * 512 + tid;
        int b = idx >> 8, d = idx & 255;
        int yi = (b * NYD + d) * NT;
        int m = mask_at(ymask, mode, yi);
        gin2[b * NYD + d] = make_float2(m ? y[yi] : 0.0f, (float)m);
    }
    __syncthreads();
    // ---- restage Wxsh with this block's W_out rows ----
    for (int i = 0; i < 2; ++i) {
        int idx = tid + 512 * i;
        int r = idx >> 8, cc = idx & 255;
        *(float4*)&Wxsh[r * 1024 + cc * 4] = *(const float4*)&W_out[(d0 + r) * NL + cc * 4];
    }

    // ---- per-lane invariants for the gates epilogue (2 outputs per lane) ----
    const float4 bir = *(const float4*)&b_ih[l0];
    const float4 bhr = *(const float4*)&b_hh[l0];
    const float4 biz = *(const float4*)&b_ih[NL + l0];
    const float4 bhz = *(const float4*)&b_hh[NL + l0];
    const float4 bin_ = *(const float4*)&b_ih[2 * NL + l0];
    const float4 bhn = *(const float4*)&b_hh[2 * NL + l0];
    int sE[2], lE[2], bE[2];
#pragma unroll
    for (int e = 0; e < 2; ++e) {
        int cidx = kl * 2 + e;
        sE[e] = cidx >> 2; lE[e] = cidx & 3;
        bE[e] = wb0 + sE[e] * 8 + bq;
    }
    // phase-B invariants
    const int bB = bt * 64 + wv * 8 + bq;          // this lane's batch in phase B
    const float boB = b_out[d0 + (kl & 3)];

    unsigned ep = 0;
    gbar(bar, ep);

    for (int t = 0; t < NT; ++t) {
        const float* hp = (t & 1) ? h1buf : h0buf;
        float*       hn = (t & 1) ? h0buf : h1buf;

        // ---- phase A: gates + h_new for 4 latent rows x 256 batches ----
        {
            float ar[4][4] = {}, az[4][4] = {}, ani[4][4] = {}, anh[4][4] = {};
            dotG<16>(ginf, 512, 0,   Wsh, bq, kl, wb0, ar, az, ani);
            dotG<32>(hp,   1024, 512, Wsh, bq, kl, wb0, ar, az, anh);
            red8(ar); red8(az); red8(ani); red8(anh);
#pragma unroll
            for (int e = 0; e < 2; ++e) {
                const int s = sE[e], l = lE[e], b = bE[e];
                float vr = sel16(ar, l, s) + c4(bir, l) + c4(bhr, l);
                float vz = sel16(az, l, s) + c4(biz, l) + c4(bhz, l);
                float vi = sel16(ani, l, s) + c4(bin_, l);
                float vh = sel16(anh, l, s) + c4(bhn, l);
                float r = sigmoidf_(vr);
                float z = sigmoidf_(vz);
                float n = tanhf(vi + r * vh);
                float hpv = hp[b * NL + l0 + l];
                hn[b * NL + l0 + l] = (1.0f - z) * n + z * hpv;
            }
        }
        gbar(bar, ep);

        // ---- phase B: out + next gin; all 256 blocks (64 d-tiles x 4 b-tiles) ----
        {
            float ac[4] = {0.f, 0.f, 0.f, 0.f};
            const float* Ab = hn + bB * NL + kl * 4;
            const float* wpo = &Wxsh[kl * 4];
            float4 A0 = *(const float4*)Ab;
#pragma unroll 1
            for (int j = 0; j < 32; ++j) {
                float4 w[4];
#pragma unroll
                for (int n = 0; n < 4; ++n) w[n] = *(const float4*)(wpo + n * 1024 + 32 * j);
                float4 Ac = A0;
                const int jn = (j + 1 < 32) ? (j + 1) : j;
                A0 = *(const float4*)(Ab + 32 * jn);
#pragma unroll
                for (int n = 0; n < 4; ++n) ac[n] += dot4f(Ac, w[n]);
            }
#pragma unroll
            for (int n = 0; n < 4; ++n) {
                float v = ac[n];
                v += __shfl_xor(v, 1, 64);
                v += __shfl_xor(v, 2, 64);
                v += __shfl_xor(v, 4, 64);
                ac[n] = v;
            }
            if (kl < 4) {
                const int d = d0 + kl;
                float o = sel4(ac, kl) + boB;
                int oidx = (bB * NYD + d) * NT + t;
                out[oidx] = o;
                if (t + 1 < NT) {
                    int yi = oidx + 1;
                    int m = mask_at(ymask, mode, yi);
                    gin2[bB * NYD + d] = make_float2(m ? y[yi] : o, (float)m);
                }
            }
        }
        gbar(bar, ep);
    }
}

// ================= fallback path (round-1, known-passing) =================

__global__ void probe_mask_kernel(const unsigned int* __restrict__ mw,
                                  int* __restrict__ flag) {
    __shared__ int not01, notf;
    if (threadIdx.x == 0) { not01 = 0; notf = 0; }
    __syncthreads();
    unsigned int v = mw[threadIdx.x];
    if (v > 1u) not01 = 1;
    if (v != 0u && v != 0x3f800000u) notf = 1;
    __syncthreads();
    if (threadIdx.x == 0) {
        int mode = 0;
        if (not01) mode = notf ? 1 : 2;
        *flag = mode;
    }
}

__global__ __launch_bounds__(256) void init_h_kernel(
        const float* __restrict__ x, const float* __restrict__ Wb,
        const float* __restrict__ bb, float* __restrict__ h0) {
    int idx = blockIdx.x * 256 + threadIdx.x;
    int b = idx >> 10;
    int l = idx & 1023;
    const float4* xr = (const float4*)(x + b * 1024);
    const float4* wr = (const float4*)(Wb + l * 1024);
    float acc = bb[l];
#pragma unroll 4
    for (int k = 0; k < 256; ++k) {
        float4 xv = xr[k];
        float4 wv = wr[k];
        acc += xv.x*wv.x + xv.y*wv.y + xv.z*wv.z + xv.w*wv.w;
    }
    h0[idx] = acc;
}

__global__ __launch_bounds__(NYD) void init_gru0_kernel(
        const float* __restrict__ y, const void* __restrict__ ymask,
        const int* __restrict__ mflag, float2* __restrict__ gin) {
    int b = blockIdx.x;
    int d = threadIdx.x;
    int mode = *mflag;
    int idx = (b * NYD + d) * NT;
    int m = mask_at(ymask, mode, idx);
    float yv = m ? y[idx] : 0.0f;
    gin[b * NYD + d] = make_float2(yv, (float)m);
}

template<int NIT>
__device__ __forceinline__ void gemm_phase(
        const float* __restrict__ A, int pitch,
        const float* __restrict__ W,
        int l0, int tid, int bg, int lth,
        float (&Ash)[16][32], float (&Wsh)[3][32][32],
        float* accr, float* accz, float* accn) {
    const int arow = tid >> 3;
    const int akc  = (tid & 7) * 4;
    float4 areg, wreg[6];
    int wrow[6], wg[6], wkc[6];
#pragma unroll
    for (int i = 0; i < 6; ++i) {
        int idx = tid + 128 * i;
        wkc[i]  = (idx & 7) * 4;
        wrow[i] = (idx >> 3) & 31;
        wg[i]   = idx >> 8;
    }
    areg = *(const float4*)(A + arow * pitch + akc);
#pragma unroll
    for (int i = 0; i < 6; ++i)
        wreg[i] = *(const float4*)(W + (wg[i]*NL + l0 + wrow[i]) * pitch + wkc[i]);
    *(float4*)&Ash[arow][akc] = areg;
#pragma unroll
    for (int i = 0; i < 6; ++i)
        *(float4*)&Wsh[wg[i]][wrow[i]][wkc[i] ^ ((wrow[i] & 7) << 2)] = wreg[i];
    __syncthreads();

    const int wsw = (lth & 7) << 2;
    for (int it = 0; it < NIT; ++it) {
        const int k0n = (it + 1) * 32;
        if (it + 1 < NIT) {
            areg = *(const float4*)(A + arow * pitch + k0n + akc);
#pragma unroll
            for (int i = 0; i < 6; ++i)
                wreg[i] = *(const float4*)(W + (wg[i]*NL + l0 + wrow[i]) * pitch + k0n + wkc[i]);
        }
#pragma unroll
        for (int kk = 0; kk < 8; ++kk) {
            float4 wr_ = *(const float4*)&Wsh[0][lth][(kk*4) ^ wsw];
            float4 wz_ = *(const float4*)&Wsh[1][lth][(kk*4) ^ wsw];
            float4 wn_ = *(const float4*)&Wsh[2][lth][(kk*4) ^ wsw];
#pragma unroll
            for (int i = 0; i < 4; ++i) {
                float4 av = *(const float4*)&Ash[bg*4 + i][kk*4];
                accr[i] += av.x*wr_.x + av.y*wr_.y + av.z*wr_.z + av.w*wr_.w;
                accz[i] += av.x*wz_.x + av.y*wz_.y + av.z*wz_.z + av.w*wz_.w;
                accn[i] += av.x*wn_.x + av.y*wn_.y + av.z*wn_.z + av.w*wn_.w;
            }
        }
        __syncthreads();
        if (it + 1 < NIT) {
            *(float4*)&Ash[arow][akc] = areg;
#pragma unroll
            for (int i = 0; i < 6; ++i)
                *(float4*)&Wsh[wg[i]][wrow[i]][wkc[i] ^ ((wrow[i] & 7) << 2)] = wreg[i];
            __syncthreads();
        }
    }
}

__global__ __launch_bounds__(128) void step_gates_kernel(
        const float* __restrict__ h_prev, float* __restrict__ h_next,
        const float* __restrict__ gin,
        const float* __restrict__ W_ih, const float* __restrict__ b_ih,
        const float* __restrict__ W_hh, const float* __restrict__ b_hh) {
    const int b0 = blockIdx.x * 16;
    const int l0 = blockIdx.y * 32;
    const int tid = threadIdx.x;
    const int lth = tid & 31;
    const int bg  = tid >> 5;
    __shared__ float Ash[16][32];
    __shared__ float Wsh[3][32][32];

    float accr[4]  = {0.f, 0.f, 0.f, 0.f};
    float accz[4]  = {0.f, 0.f, 0.f, 0.f};
    float accni[4] = {0.f, 0.f, 0.f, 0.f};
    float accnh[4] = {0.f, 0.f, 0.f, 0.f};

    gemm_phase<KIN/32>(gin    + b0*KIN, KIN, W_ih, l0, tid, bg, lth, Ash, Wsh, accr, accz, accni);
    gemm_phase<NL/32 >(h_prev + b0*NL,  NL,  W_hh, l0, tid, bg, lth, Ash, Wsh, accr, accz, accnh);

    const int l = l0 + lth;
    const float br  = b_ih[l]        + b_hh[l];
    const float bz  = b_ih[NL + l]   + b_hh[NL + l];
    const float bni = b_ih[2*NL + l];
    const float bnh = b_hh[2*NL + l];
#pragma unroll
    for (int i = 0; i < 4; ++i) {
        const int b = b0 + bg*4 + i;
        float r = sigmoidf_(accr[i] + br);
        float z = sigmoidf_(accz[i] + bz);
        float n = tanhf(accni[i] + bni + r * (accnh[i] + bnh));
        float hp = h_prev[b*NL + l];
        h_next[b*NL + l] = (1.0f - z)*n + z*hp;
    }
}

__global__ __launch_bounds__(128) void step_out_kernel(
        const float* __restrict__ h, const float* __restrict__ W_out,
        const float* __restrict__ b_out, const float* __restrict__ y,
        const void* __restrict__ ymask, const int* __restrict__ mflag,
        float* __restrict__ out, float2* __restrict__ gin, int t) {
    const int b0 = blockIdx.x * 16;
    const int d0 = blockIdx.y * 32;
    const int tid = threadIdx.x;
    const int dth = tid & 31;
    const int bg  = tid >> 5;
    __shared__ float Ash[16][32];
    __shared__ float Wsh[32][32];
    float acc[4] = {0.f, 0.f, 0.f, 0.f};

    const int arow = tid >> 3;
    const int akc  = (tid & 7) * 4;
    float4 areg, wreg[2];
    int wrow[2], wkc[2];
#pragma unroll
    for (int i = 0; i < 2; ++i) {
        int idx = tid + 128 * i;
        wkc[i]  = (idx & 7) * 4;
        wrow[i] = idx >> 3;
    }
    const float* A = h + b0 * NL;
    areg = *(const float4*)(A + arow * NL + akc);
#pragma unroll
    for (int i = 0; i < 2; ++i)
        wreg[i] = *(const float4*)(W_out + (d0 + wrow[i]) * NL + wkc[i]);
    *(float4*)&Ash[arow][akc] = areg;
#pragma unroll
    for (int i = 0; i < 2; ++i)
        *(float4*)&Wsh[wrow[i]][wkc[i] ^ ((wrow[i] & 7) << 2)] = wreg[i];
    __syncthreads();

    const int wsw = (dth & 7) << 2;
    for (int it = 0; it < NL/32; ++it) {
        const int k0n = (it + 1) * 32;
        if (it + 1 < NL/32) {
            areg = *(const float4*)(A + arow * NL + k0n + akc);
#pragma unroll
            for (int i = 0; i < 2; ++i)
                wreg[i] = *(const float4*)(W_out + (d0 + wrow[i]) * NL + k0n + wkc[i]);
        }
#pragma unroll
        for (int kk = 0; kk < 8; ++kk) {
            float4 wv = *(const float4*)&Wsh[dth][(kk*4) ^ wsw];
#pragma unroll
            for (int i = 0; i < 4; ++i) {
                float4 av = *(const float4*)&Ash[bg*4 + i][kk*4];
                acc[i] += av.x*wv.x + av.y*wv.y + av.z*wv.z + av.w*wv.w;
            }
        }
        __syncthreads();
        if (it + 1 < NL/32) {
            *(float4*)&Ash[arow][akc] = areg;
#pragma unroll
            for (int i = 0; i < 2; ++i)
                *(float4*)&Wsh[wrow[i]][wkc[i] ^ ((wrow[i] & 7) << 2)] = wreg[i];
            __syncthreads();
        }
    }

    const int d = d0 + dth;
    const float bo = b_out[d];
    const int mode = *mflag;
#pragma unroll
    for (int i = 0; i < 4; ++i) {
        const int b = b0 + bg*4 + i;
        float o = acc[i] + bo;
        out[(b*NYD + d)*NT + t] = o;
        if (t + 1 < NT) {
            int idx = (b*NYD + d)*NT + (t + 1);
            int m = mask_at(ymask, mode, idx);
            float yv = m ? y[idx] : o;
            gin[b*NYD + d] = make_float2(yv, (float)m);
        }
    }
}

// ================= launch =================

extern "C" void kernel_launch(void* const* d_in, const int* in_sizes, int n_in,
                              void* d_out, int out_size, void* d_ws, size_t ws_size,
                              hipStream_t stream) {
    (void)in_sizes; (void)n_in; (void)out_size; (void)ws_size;
    const float* x      = (const float*)d_in[0];
    const float* y      = (const float*)d_in[1];
    const void*  ymask  = d_in[2];
    const float* W_beta = (const float*)d_in[3];
    const float* b_beta = (const float*)d_in[4];
    const float* W_ih   = (const float*)d_in[5];
    const float* b_ih   = (const float*)d_in[6];
    const float* W_hh   = (const float*)d_in[7];
    const float* b_hh   = (const float*)d_in[8];
    const float* W_out  = (const float*)d_in[9];
    const float* b_out  = (const float*)d_in[10];
    float* out = (float*)d_out;

    float*    ws    = (float*)d_ws;
    float*    h0buf = ws;                               // 1 MB
    float*    h1buf = ws + NB * NL;                     // 1 MB
    float2*   gin2  = (float2*)(ws + 2 * NB * NL);      // 512 KB
    unsigned* bar   = (unsigned*)(ws + 2 * NB * NL + 2 * NB * NYD);   // 4 KB
    int*      mflag = (int*)(bar + 1024);

    zero_bar_kernel<<<4, 256, 0, stream>>>(bar);

    void* args[] = { (void*)&x, (void*)&y, (void*)&ymask,
                     (void*)&W_beta, (void*)&b_beta,
                     (void*)&W_ih, (void*)&b_ih,
                     (void*)&W_hh, (void*)&b_hh,
                     (void*)&W_out, (void*)&b_out,
                     (void*)&out, (void*)&h0buf, (void*)&h1buf,
                     (void*)&gin2, (void*)&bar };
    hipError_t err = hipLaunchCooperativeKernel((const void*)gru_persist,
                                                dim3(256), dim3(512),
                                                args, 0, stream);
    if (err != hipSuccess) {
        // deterministic per-environment fallback: round-1 proven per-step path
        probe_mask_kernel<<<1, 256, 0, stream>>>((const unsigned int*)ymask, mflag);
        init_h_kernel<<<NB*NL/256, 256, 0, stream>>>(x, W_beta, b_beta, h0buf);
        init_gru0_kernel<<<NB, NYD, 0, stream>>>(y, ymask, mflag, gin2);
        for (int t = 0; t < NT; ++t) {
            float* hp = (t & 1) ? h1buf : h0buf;
            float* hn = (t & 1) ? h0buf : h1buf;
            dim3 ggrid(16, 32);
            step_gates_kernel<<<ggrid, 128, 0, stream>>>(
                hp, hn, (const float*)gin2, W_ih, b_ih, W_hh, b_hh);
            dim3 ogrid(16, 8);
            step_out_kernel<<<ogrid, 128, 0, stream>>>(
                hn, W_out, b_out, y, ymask, mflag, out, gin2, t);
        }
    }
}